// Round 4
// baseline (1599.246 us; speedup 1.0000x reference)
//
#include <hip/hip_runtime.h>

typedef unsigned short u16;
typedef unsigned int u32;

typedef __bf16 bf16x8 __attribute__((ext_vector_type(8)));
typedef float f32x4 __attribute__((ext_vector_type(4)));

#define DIM 768
#define HID 3072
#define NTOK 196
#define BT 128
#define NTOKENS (BT * NTOK)   // 25088
#define MJ 3136               // FRAMES * NTOK
#define HEADS 12

// workspace layout sizes (bytes)
#define SZ_WB   ((size_t)(2304*768 + 768*768 + 3072*768 + 768*3072) * 2)  // bf16 weights
#define SZ_XN   ((size_t)NTOKENS * DIM * 2)
#define SZ_QKV  ((size_t)NTOKENS * 2304 * 2)
#define SZ_X2   ((size_t)NTOKENS * DIM * 4)
#define SZ_HDN  ((size_t)NTOKENS * HID * 2)
#define SZ_KV   ((size_t)96 * 4096 * 4)
#define SZ_KS   ((size_t)96 * 64 * 4)
#define WS_NEED (SZ_WB + SZ_XN + SZ_QKV + SZ_X2 + SZ_HDN + SZ_KV + SZ_KS)

// Fallback scratch allocated at dlopen time (hipMalloc is forbidden only
// inside kernel_launch / graph capture). Used iff ws_size < WS_NEED.
static void* g_buf = nullptr;
struct WsInit {
  WsInit() { (void)hipMalloc(&g_buf, WS_NEED); }
};
static WsInit g_wsinit;

__device__ __forceinline__ float b2f(u16 u) {
  union { u32 i; float f; } x; x.i = ((u32)u) << 16; return x.f;
}
__device__ __forceinline__ u16 f2b(float f) {
  u32 x = __float_as_uint(f);
  return (u16)((x + 0x7fffu + ((x >> 16) & 1u)) >> 16);
}

// async 16B global->LDS (gfx950). LDS dest = wave-uniform base + lane*16.
__device__ __forceinline__ void gload_lds16(const u16* g, u16* l) {
  __builtin_amdgcn_global_load_lds(
      (const __attribute__((address_space(1))) u32*)g,
      (__attribute__((address_space(3))) u32*)l, 16, 0, 0);
}

// ---------------- f32 -> bf16 conversion (weights) ----------------
__global__ __launch_bounds__(256) void cvt_f32_bf16(const float* __restrict__ in,
    u16* __restrict__ out, int n4)
{
  int i = blockIdx.x * 256 + threadIdx.x;
  if (i < n4) {
    float4 f = ((const float4*)in)[i];
    ushort4 r;
    r.x = f2b(f.x); r.y = f2b(f.y); r.z = f2b(f.z); r.w = f2b(f.w);
    ((ushort4*)out)[i] = r;
  }
}

// ---------------- zero-fill for KV/KS accumulators ----------------
__global__ __launch_bounds__(256) void zero_f32(float* __restrict__ p, int n) {
  int i = blockIdx.x * 256 + threadIdx.x;
  if (i < n) p[i] = 0.0f;
}

// ---------------- LayerNorm: one wave per token, fp32 in, bf16 out ---------
__global__ __launch_bounds__(256) void ln_kernel(const float* __restrict__ xin,
    const float* __restrict__ w, const float* __restrict__ b, u16* __restrict__ out)
{
  const int token = blockIdx.x * 4 + (threadIdx.x >> 6);
  const int lane = threadIdx.x & 63;
  float v[12];
  const float* x = xin + (size_t)token * DIM;
#pragma unroll
  for (int c = 0; c < 3; ++c) {
    float4 f = *(const float4*)(x + c * 256 + lane * 4);
    v[c*4+0] = f.x; v[c*4+1] = f.y; v[c*4+2] = f.z; v[c*4+3] = f.w;
  }
  float s = 0.f, sq = 0.f;
#pragma unroll
  for (int i = 0; i < 12; ++i) { s += v[i]; sq += v[i] * v[i]; }
#pragma unroll
  for (int off = 32; off > 0; off >>= 1) {
    s += __shfl_xor(s, off, 64);
    sq += __shfl_xor(sq, off, 64);
  }
  const float mean = s * (1.0f / 768.0f);
  const float var = sq * (1.0f / 768.0f) - mean * mean;
  const float rstd = rsqrtf(var + 1e-5f);
  u16* o = out + (size_t)token * DIM;
#pragma unroll
  for (int c = 0; c < 3; ++c) {
    float4 wv = *(const float4*)(w + c * 256 + lane * 4);
    float4 bv = *(const float4*)(b + c * 256 + lane * 4);
    ushort4 r;
    r.x = f2b((v[c*4+0] - mean) * rstd * wv.x + bv.x);
    r.y = f2b((v[c*4+1] - mean) * rstd * wv.y + bv.y);
    r.z = f2b((v[c*4+2] - mean) * rstd * wv.z + bv.z);
    r.w = f2b((v[c*4+3] - mean) * rstd * wv.w + bv.w);
    *(ushort4*)(o + c * 256 + lane * 4) = r;
  }
}

// ---------------- MFMA GEMM: C[M,N] = A[M,K] * W[N,K]^T, fused epilogues ----
// K-loop: global_load_lds width-16 staging into a chunk-major LDS layout.
// LDS: 8 wave-blocks of 1 KB per tile; block holds 16 rows x 32 u16 with
//   byte addr = chunk*256 + row*16  (chunk = 8-u16 group of K)
// -> staged by one global_load_lds per wave-block (lane = chunk*16+row),
//    read by ds_read_b128 with 8 consecutive lanes covering all 32 banks.
// MODE 0: QKV  (no bias; relu+0.125 on cols < 1536; bf16 out)
// MODE 1: PROJ (fp32 bias + fp32 residual; fp32 out)
// MODE 2: FC1  (fp32 bias; bf16 out)
// MODE 3: FC2  (fp32 bias + fp32 residual; fp32 out)
template<int MODE>
__global__ __launch_bounds__(256) void gemm_bt(
    const u16* __restrict__ A, const u16* __restrict__ W,
    const float* __restrict__ bias, const float* __restrict__ res,
    void* __restrict__ out, int M, int N, int K)
{
  __shared__ __align__(16) u16 As[128 * 32];   // 8 KB
  __shared__ __align__(16) u16 Bs[128 * 32];   // 8 KB
  const int t = threadIdx.x;
  const int lane = t & 63;
  const int wv = t >> 6;            // 0..3
  const int m0 = blockIdx.y * 128;
  const int n0 = blockIdx.x * 128;

  // staging: wave wv stages A wave-blocks {2wv,2wv+1} and same for B.
  // lane -> (row = lane&15, chunk = lane>>4) within a 16-row block.
  const int srow = lane & 15;
  const int schunk = lane >> 4;
  const u16* gA0 = A + (size_t)(m0 + 2 * wv * 16 + srow) * K + schunk * 8;
  const u16* gA1 = A + (size_t)(m0 + (2 * wv + 1) * 16 + srow) * K + schunk * 8;
  const u16* gB0 = W + (size_t)(n0 + 2 * wv * 16 + srow) * K + schunk * 8;
  const u16* gB1 = W + (size_t)(n0 + (2 * wv + 1) * 16 + srow) * K + schunk * 8;
  u16* lA0 = &As[(2 * wv) * 512];
  u16* lA1 = &As[(2 * wv + 1) * 512];
  u16* lB0 = &Bs[(2 * wv) * 512];
  u16* lB1 = &Bs[(2 * wv + 1) * 512];

  const int lm = lane & 15;
  const int q = lane >> 4;
  const int ab = (wv & 1) * 4;      // A wave-block base for compute
  const int bb = (wv >> 1) * 4;     // B wave-block base

  f32x4 acc[4][4];
#pragma unroll
  for (int i = 0; i < 4; ++i)
#pragma unroll
    for (int j = 0; j < 4; ++j) acc[i][j] = (f32x4){0.f, 0.f, 0.f, 0.f};

  for (int k0 = 0; k0 < K; k0 += 32) {
    __syncthreads();
    gload_lds16(gA0 + k0, lA0);
    gload_lds16(gA1 + k0, lA1);
    gload_lds16(gB0 + k0, lB0);
    gload_lds16(gB1 + k0, lB1);
    __syncthreads();   // compiler emits s_waitcnt vmcnt(0) before barrier
    bf16x8 af[4], bfv[4];
#pragma unroll
    for (int mi = 0; mi < 4; ++mi)
      af[mi] = *(const bf16x8*)&As[(ab + mi) * 512 + q * 128 + lm * 8];
#pragma unroll
    for (int ni = 0; ni < 4; ++ni)
      bfv[ni] = *(const bf16x8*)&Bs[(bb + ni) * 512 + q * 128 + lm * 8];
#pragma unroll
    for (int mi = 0; mi < 4; ++mi)
#pragma unroll
      for (int ni = 0; ni < 4; ++ni)
        acc[mi][ni] = __builtin_amdgcn_mfma_f32_16x16x32_bf16(af[mi], bfv[ni], acc[mi][ni], 0, 0, 0);
  }

  const int wm = (wv & 1) << 6;
  const int wn = (wv >> 1) << 6;
  const int quad = q;
#pragma unroll
  for (int mi = 0; mi < 4; ++mi) {
    const int rbase = m0 + wm + mi * 16 + quad * 4;
#pragma unroll
    for (int ni = 0; ni < 4; ++ni) {
      const int col = n0 + wn + ni * 16 + lm;
      float bv = 0.f;
      if (MODE != 0) bv = bias[col];
#pragma unroll
      for (int r = 0; r < 4; ++r) {
        float v = acc[mi][ni][r];
        const size_t idx = (size_t)(rbase + r) * N + col;
        if (MODE == 0) {
          if (col < 1536) v = fmaxf(v, 0.0f) + 0.125f;
          ((u16*)out)[idx] = f2b(v);
        } else if (MODE == 1) {
          ((float*)out)[idx] = v + bv + res[idx];
        } else if (MODE == 2) {
          ((u16*)out)[idx] = f2b(v + bv);
        } else {
          ((float*)out)[idx] = v + bv + res[idx];
        }
      }
    }
  }
}

// ---------------- kv = sum_m k_ (outer) v ; ksum = sum_m k_  ----------------
// grid (96, 8): bh pair, m-split. Accumulate with fp32 atomics.
__global__ __launch_bounds__(256) void kv_reduce(const u16* __restrict__ qkv,
    float* __restrict__ kv, float* __restrict__ ksum)
{
  const int bh = blockIdx.x;       // b*12+h
  const int s = blockIdx.y;        // 0..7
  const int b = bh / 12, h = bh % 12;
  __shared__ __align__(16) u16 ks[64 * 64];
  __shared__ __align__(16) u16 vs[64 * 64];
  const int t = threadIdx.x;
  const int e = t & 63;
  const int dg = (t >> 6) * 16;

  float acc[16];
#pragma unroll
  for (int j = 0; j < 16; ++j) acc[j] = 0.f;
  float ksacc = 0.f;

  for (int ch = s; ch < 49; ch += 8) {
    const size_t tokbase = (size_t)b * MJ + ch * 64;
    __syncthreads();
#pragma unroll
    for (int i = 0; i < 2; ++i) {
      int c = t + i * 256;
      int row = c >> 3, eo = (c & 7) * 8;
      const u16* base = qkv + (tokbase + row) * 2304 + h * 64 + eo;
      *(uint4*)&ks[row * 64 + eo] = *(const uint4*)(base + 768);
      *(uint4*)&vs[row * 64 + eo] = *(const uint4*)(base + 1536);
    }
    __syncthreads();
    for (int m = 0; m < 64; ++m) {
      float kf = b2f(ks[m * 64 + e]);
      ksacc += kf;
      bf16x8 v0 = *(const bf16x8*)&vs[m * 64 + dg];
      bf16x8 v1 = *(const bf16x8*)&vs[m * 64 + dg + 8];
#pragma unroll
      for (int j = 0; j < 8; ++j) {
        acc[j]     += kf * (float)v0[j];
        acc[j + 8] += kf * (float)v1[j];
      }
    }
  }
  float* dst = kv + (size_t)bh * 4096 + e * 64 + dg;
#pragma unroll
  for (int j = 0; j < 16; ++j) atomicAdd(&dst[j], acc[j]);
  if (dg == 0) atomicAdd(&ksum[bh * 64 + e], ksacc);
}

// ---------------- out = (q_ @ kv) * z ----------------
__global__ __launch_bounds__(256) void attn_out(const u16* __restrict__ qkv,
    const float* __restrict__ kv, const float* __restrict__ ksum,
    u16* __restrict__ outp)
{
  const int chunk = blockIdx.x;   // 0..48
  const int h = blockIdx.y;       // 0..11
  const int b = blockIdx.z;       // 0..7
  __shared__ float kvs[4096];
  __shared__ float kss[64];
  const int t = threadIdx.x;
  const float* kvsrc = kv + (size_t)(b * 12 + h) * 4096;
  for (int i = t; i < 1024; i += 256)
    ((float4*)kvs)[i] = ((const float4*)kvsrc)[i];
  if (t < 64) kss[t] = ksum[(b * 12 + h) * 64 + t];
  __syncthreads();
  const int wv = t >> 6, lane = t & 63;
  for (int i = 0; i < 16; ++i) {
    const int m = chunk * 64 + wv * 16 + i;
    const size_t token = (size_t)b * MJ + m;
    float q = b2f(qkv[token * 2304 + h * 64 + lane]);
    float pd = q * kss[lane];
#pragma unroll
    for (int off = 32; off > 0; off >>= 1) pd += __shfl_xor(pd, off, 64);
    const float z = 1.0f / (pd + 1e-6f);
    float o = 0.f;
    for (int e = 0; e < 64; ++e) o += __shfl(q, e, 64) * kvs[e * 64 + lane];
    outp[token * 768 + h * 64 + lane] = f2b(o * z);
  }
}

// ---------------- depthwise 3x3 conv + exact GELU, in place --------------
__global__ __launch_bounds__(256) void dwconv_gelu(u16* __restrict__ hdn,
    const float* __restrict__ w, const float* __restrict__ bias)
{
  __shared__ u16 pl[196 * 64];
  const int cb = blockIdx.x;     // 0..47
  const int fr = blockIdx.y;     // 0..127
  const int t = threadIdx.x;
  const int c0 = cb * 64;
  u16* base = hdn + (size_t)fr * 196 * HID + c0;
  for (int i = 0; i < 49; ++i) {
    int idx = i * 256 + t;
    int p = idx >> 6, c = idx & 63;
    pl[idx] = base[(size_t)p * HID + c];
  }
  __syncthreads();
  const int c = t & 63;
  const int pg = t >> 6;
  float wr[9];
#pragma unroll
  for (int k = 0; k < 9; ++k) wr[k] = w[(c0 + c) * 9 + k];
  const float bv = bias[c0 + c];
  for (int j = 0; j < 49; ++j) {
    const int p = pg + j * 4;
    const int py = p / 14, px = p % 14;
    float a = bv;
#pragma unroll
    for (int ky = 0; ky < 3; ++ky) {
      int yy = py + ky - 1;
      if (yy < 0 || yy > 13) continue;
#pragma unroll
      for (int kx = 0; kx < 3; ++kx) {
        int xx = px + kx - 1;
        if (xx < 0 || xx > 13) continue;
        a += wr[ky * 3 + kx] * b2f(pl[(yy * 14 + xx) * 64 + c]);
      }
    }
    float g = 0.5f * a * (1.0f + erff(a * 0.70710678118654752f));
    base[(size_t)p * HID + c] = f2b(g);
  }
}

extern "C" void kernel_launch(void* const* d_in, const int* in_sizes, int n_in,
                              void* d_out, int out_size, void* d_ws, size_t ws_size,
                              hipStream_t stream)
{
  (void)in_sizes; (void)n_in; (void)out_size;
  const float* x     = (const float*)d_in[0];
  const float* ln1w  = (const float*)d_in[1];
  const float* ln1b  = (const float*)d_in[2];
  const float* qkvw  = (const float*)d_in[3];
  const float* projw = (const float*)d_in[4];
  const float* projb = (const float*)d_in[5];
  const float* ln2w  = (const float*)d_in[6];
  const float* ln2b  = (const float*)d_in[7];
  const float* fc1w  = (const float*)d_in[8];
  const float* fc1b  = (const float*)d_in[9];
  const float* dww   = (const float*)d_in[10];
  const float* dwb   = (const float*)d_in[11];
  const float* fc2w  = (const float*)d_in[12];
  const float* fc2b  = (const float*)d_in[13];

  // constant across calls: same branch every launch
  char* p = (ws_size >= WS_NEED) ? (char*)d_ws : (char*)g_buf;
  u16* WQKV  = (u16*)p;   p += (size_t)2304 * 768 * 2;
  u16* WPROJ = (u16*)p;   p += (size_t)768 * 768 * 2;
  u16* WFC1  = (u16*)p;   p += (size_t)3072 * 768 * 2;
  u16* WFC2  = (u16*)p;   p += (size_t)768 * 3072 * 2;
  u16* XN    = (u16*)p;   p += SZ_XN;    // xn1 / attn_out
  u16* QKV   = (u16*)p;   p += SZ_QKV;   // q_,k_,v  / xn2
  float* X2  = (float*)p; p += SZ_X2;    // residual after attn (fp32)
  u16* HDN   = (u16*)p;   p += SZ_HDN;   // fc1 out, conv in place
  float* KV  = (float*)p; p += SZ_KV;
  float* KS  = (float*)p; p += SZ_KS;

  // convert weights to bf16 (same work every call)
  cvt_f32_bf16<<<(2304*768/4 + 255)/256, 256, 0, stream>>>(qkvw, WQKV, 2304*768/4);
  cvt_f32_bf16<<<(768*768/4 + 255)/256, 256, 0, stream>>>(projw, WPROJ, 768*768/4);
  cvt_f32_bf16<<<(3072*768/4 + 255)/256, 256, 0, stream>>>(fc1w, WFC1, 3072*768/4);
  cvt_f32_bf16<<<(768*3072/4 + 255)/256, 256, 0, stream>>>(fc2w, WFC2, 768*3072/4);

  const int nz = 96 * 4096 + 96 * 64;    // KV and KS are contiguous
  zero_f32<<<(nz + 255) / 256, 256, 0, stream>>>(KV, nz);
  ln_kernel<<<NTOKENS / 4, 256, 0, stream>>>(x, ln1w, ln1b, XN);
  gemm_bt<0><<<dim3(18, 196), 256, 0, stream>>>(XN, WQKV, nullptr, nullptr, QKV, NTOKENS, 2304, 768);
  kv_reduce<<<dim3(96, 8), 256, 0, stream>>>(QKV, KV, KS);
  attn_out<<<dim3(49, 12, 8), 256, 0, stream>>>(QKV, KV, KS, XN);
  gemm_bt<1><<<dim3(6, 196), 256, 0, stream>>>(XN, WPROJ, projb, x, X2, NTOKENS, 768, 768);
  ln_kernel<<<NTOKENS / 4, 256, 0, stream>>>(X2, ln2w, ln2b, QKV);
  gemm_bt<2><<<dim3(24, 196), 256, 0, stream>>>(QKV, WFC1, fc1b, nullptr, HDN, NTOKENS, 3072, 768);
  dwconv_gelu<<<dim3(48, 128), 256, 0, stream>>>(HDN, dww, dwb);
  gemm_bt<3><<<dim3(6, 196), 256, 0, stream>>>(HDN, WFC2, fc2b, X2, (float*)d_out, NTOKENS, 768, 3072);
}

// Round 5
// 1563.343 us; speedup vs baseline: 1.0230x; 1.0230x over previous
//
#include <hip/hip_runtime.h>

typedef unsigned short u16;
typedef unsigned int u32;

typedef __bf16 bf16x8 __attribute__((ext_vector_type(8)));
typedef float f32x4 __attribute__((ext_vector_type(4)));

#define DIM 768
#define HID 3072
#define NTOK 196
#define BT 128
#define NTOKENS (BT * NTOK)   // 25088
#define MJ 3136               // FRAMES * NTOK
#define HEADS 12

// workspace layout sizes (bytes)
#define SZ_WB   ((size_t)(2304*768 + 768*768 + 3072*768 + 768*3072) * 2)  // bf16 weights
#define SZ_XN   ((size_t)NTOKENS * DIM * 2)
#define SZ_QKV  ((size_t)NTOKENS * 2304 * 2)
#define SZ_X2   ((size_t)NTOKENS * DIM * 4)
#define SZ_HDN  ((size_t)NTOKENS * HID * 2)
#define SZ_KV   ((size_t)96 * 4096 * 4)
#define SZ_KS   ((size_t)96 * 64 * 4)
#define WS_NEED (SZ_WB + SZ_XN + SZ_QKV + SZ_X2 + SZ_HDN + SZ_KV + SZ_KS)

// Fallback scratch allocated at dlopen time (hipMalloc is forbidden only
// inside kernel_launch / graph capture). Used iff ws_size < WS_NEED.
static void* g_buf = nullptr;
struct WsInit {
  WsInit() { (void)hipMalloc(&g_buf, WS_NEED); }
};
static WsInit g_wsinit;

__device__ __forceinline__ float b2f(u16 u) {
  union { u32 i; float f; } x; x.i = ((u32)u) << 16; return x.f;
}
__device__ __forceinline__ u16 f2b(float f) {
  u32 x = __float_as_uint(f);
  return (u16)((x + 0x7fffu + ((x >> 16) & 1u)) >> 16);
}

// async 16B global->LDS (gfx950). LDS dest = wave-uniform base + lane*16.
__device__ __forceinline__ void gload_lds16(const u16* g, u16* l) {
  __builtin_amdgcn_global_load_lds(
      (const __attribute__((address_space(1))) u32*)g,
      (__attribute__((address_space(3))) u32*)l, 16, 0, 0);
}

// ---------------- f32 -> bf16 conversion (weights) ----------------
__global__ __launch_bounds__(256) void cvt_f32_bf16(const float* __restrict__ in,
    u16* __restrict__ out, int n4)
{
  int i = blockIdx.x * 256 + threadIdx.x;
  if (i < n4) {
    float4 f = ((const float4*)in)[i];
    ushort4 r;
    r.x = f2b(f.x); r.y = f2b(f.y); r.z = f2b(f.z); r.w = f2b(f.w);
    ((ushort4*)out)[i] = r;
  }
}

// ---------------- zero-fill for KV/KS accumulators ----------------
__global__ __launch_bounds__(256) void zero_f32(float* __restrict__ p, int n) {
  int i = blockIdx.x * 256 + threadIdx.x;
  if (i < n) p[i] = 0.0f;
}

// ---------------- LayerNorm: one wave per token, fp32 in, bf16 out ---------
__global__ __launch_bounds__(256) void ln_kernel(const float* __restrict__ xin,
    const float* __restrict__ w, const float* __restrict__ b, u16* __restrict__ out)
{
  const int token = blockIdx.x * 4 + (threadIdx.x >> 6);
  const int lane = threadIdx.x & 63;
  float v[12];
  const float* x = xin + (size_t)token * DIM;
#pragma unroll
  for (int c = 0; c < 3; ++c) {
    float4 f = *(const float4*)(x + c * 256 + lane * 4);
    v[c*4+0] = f.x; v[c*4+1] = f.y; v[c*4+2] = f.z; v[c*4+3] = f.w;
  }
  float s = 0.f, sq = 0.f;
#pragma unroll
  for (int i = 0; i < 12; ++i) { s += v[i]; sq += v[i] * v[i]; }
#pragma unroll
  for (int off = 32; off > 0; off >>= 1) {
    s += __shfl_xor(s, off, 64);
    sq += __shfl_xor(sq, off, 64);
  }
  const float mean = s * (1.0f / 768.0f);
  const float var = sq * (1.0f / 768.0f) - mean * mean;
  const float rstd = rsqrtf(var + 1e-5f);
  u16* o = out + (size_t)token * DIM;
#pragma unroll
  for (int c = 0; c < 3; ++c) {
    float4 wv = *(const float4*)(w + c * 256 + lane * 4);
    float4 bv = *(const float4*)(b + c * 256 + lane * 4);
    ushort4 r;
    r.x = f2b((v[c*4+0] - mean) * rstd * wv.x + bv.x);
    r.y = f2b((v[c*4+1] - mean) * rstd * wv.y + bv.y);
    r.z = f2b((v[c*4+2] - mean) * rstd * wv.z + bv.z);
    r.w = f2b((v[c*4+3] - mean) * rstd * wv.w + bv.w);
    *(ushort4*)(o + c * 256 + lane * 4) = r;
  }
}

// ---------------- MFMA GEMM: C[M,N] = A[M,K] * W[N,K]^T, fused epilogues ----
// K-loop: DOUBLE-BUFFERED global_load_lds staging, ONE barrier per iteration:
//   barrier; issue async loads tile t+1 -> buf^1; ds_read+MFMA tile t from buf.
// Prefetch overlaps compute; compiler's s_waitcnt vmcnt(0) before s_barrier
// guarantees tile t+1 landed before it is read next iteration.
// LDS layout per tile: 8 wave-blocks of 1 KB; block = 16 rows x 32 u16,
//   byte addr = chunk*256 + row*16 (conflict-free for ds_read_b128 frags).
// MODE 0: QKV  (no bias; relu+0.125 on cols < 1536; bf16 out)
// MODE 1: PROJ (fp32 bias + fp32 residual; fp32 out)
// MODE 2: FC1  (fp32 bias; bf16 out)
// MODE 3: FC2  (fp32 bias + fp32 residual; fp32 out)
template<int MODE>
__global__ __launch_bounds__(256) void gemm_bt(
    const u16* __restrict__ A, const u16* __restrict__ W,
    const float* __restrict__ bias, const float* __restrict__ res,
    void* __restrict__ out, int M, int N, int K)
{
  __shared__ __align__(16) u16 As[2][128 * 32];   // 2 x 8 KB
  __shared__ __align__(16) u16 Bs[2][128 * 32];   // 2 x 8 KB
  const int t = threadIdx.x;
  const int lane = t & 63;
  const int wv = t >> 6;            // 0..3
  const int m0 = blockIdx.y * 128;
  const int n0 = blockIdx.x * 128;

  // staging: wave wv stages A wave-blocks {2wv,2wv+1} and same for B.
  // lane -> (row = lane&15, chunk = lane>>4) within a 16-row block.
  const int srow = lane & 15;
  const int schunk = lane >> 4;
  const u16* gA0 = A + (size_t)(m0 + 2 * wv * 16 + srow) * K + schunk * 8;
  const u16* gA1 = A + (size_t)(m0 + (2 * wv + 1) * 16 + srow) * K + schunk * 8;
  const u16* gB0 = W + (size_t)(n0 + 2 * wv * 16 + srow) * K + schunk * 8;
  const u16* gB1 = W + (size_t)(n0 + (2 * wv + 1) * 16 + srow) * K + schunk * 8;
  const int lo0 = (2 * wv) * 512;
  const int lo1 = (2 * wv + 1) * 512;

  const int lm = lane & 15;
  const int q = lane >> 4;
  const int ab = (wv & 1) * 4;      // A wave-block base for compute
  const int bb = (wv >> 1) * 4;     // B wave-block base

  f32x4 acc[4][4];
#pragma unroll
  for (int i = 0; i < 4; ++i)
#pragma unroll
    for (int j = 0; j < 4; ++j) acc[i][j] = (f32x4){0.f, 0.f, 0.f, 0.f};

  const int nt = K >> 5;
  // prologue: stage tile 0 into buffer 0
  gload_lds16(gA0, &As[0][lo0]);
  gload_lds16(gA1, &As[0][lo1]);
  gload_lds16(gB0, &Bs[0][lo0]);
  gload_lds16(gB1, &Bs[0][lo1]);

  for (int ti = 0; ti < nt; ++ti) {
    __syncthreads();   // drains tile-ti loads (vmcnt) + prev buffer reads (lgkm)
    const int cur = ti & 1;
    if (ti + 1 < nt) {
      const int k1 = (ti + 1) << 5;
      const int nxt = cur ^ 1;
      gload_lds16(gA0 + k1, &As[nxt][lo0]);
      gload_lds16(gA1 + k1, &As[nxt][lo1]);
      gload_lds16(gB0 + k1, &Bs[nxt][lo0]);
      gload_lds16(gB1 + k1, &Bs[nxt][lo1]);
    }
    bf16x8 af[4], bfv[4];
#pragma unroll
    for (int mi = 0; mi < 4; ++mi)
      af[mi] = *(const bf16x8*)&As[cur][(ab + mi) * 512 + q * 128 + lm * 8];
#pragma unroll
    for (int ni = 0; ni < 4; ++ni)
      bfv[ni] = *(const bf16x8*)&Bs[cur][(bb + ni) * 512 + q * 128 + lm * 8];
#pragma unroll
    for (int mi = 0; mi < 4; ++mi)
#pragma unroll
      for (int ni = 0; ni < 4; ++ni)
        acc[mi][ni] = __builtin_amdgcn_mfma_f32_16x16x32_bf16(af[mi], bfv[ni], acc[mi][ni], 0, 0, 0);
  }

  const int wm = (wv & 1) << 6;
  const int wn = (wv >> 1) << 6;
  const int quad = q;
#pragma unroll
  for (int mi = 0; mi < 4; ++mi) {
    const int rbase = m0 + wm + mi * 16 + quad * 4;
#pragma unroll
    for (int ni = 0; ni < 4; ++ni) {
      const int col = n0 + wn + ni * 16 + lm;
      float bv = 0.f;
      if (MODE != 0) bv = bias[col];
#pragma unroll
      for (int r = 0; r < 4; ++r) {
        float v = acc[mi][ni][r];
        const size_t idx = (size_t)(rbase + r) * N + col;
        if (MODE == 0) {
          if (col < 1536) v = fmaxf(v, 0.0f) + 0.125f;
          ((u16*)out)[idx] = f2b(v);
        } else if (MODE == 1) {
          ((float*)out)[idx] = v + bv + res[idx];
        } else if (MODE == 2) {
          ((u16*)out)[idx] = f2b(v + bv);
        } else {
          ((float*)out)[idx] = v + bv + res[idx];
        }
      }
    }
  }
}

// ---------------- kv = sum_m k_ (outer) v ; ksum = sum_m k_  ----------------
// grid (96, 8): bh pair, m-split. Accumulate with fp32 atomics.
__global__ __launch_bounds__(256) void kv_reduce(const u16* __restrict__ qkv,
    float* __restrict__ kv, float* __restrict__ ksum)
{
  const int bh = blockIdx.x;       // b*12+h
  const int s = blockIdx.y;        // 0..7
  const int b = bh / 12, h = bh % 12;
  __shared__ __align__(16) u16 ks[64 * 64];
  __shared__ __align__(16) u16 vs[64 * 64];
  const int t = threadIdx.x;
  const int e = t & 63;
  const int dg = (t >> 6) * 16;

  float acc[16];
#pragma unroll
  for (int j = 0; j < 16; ++j) acc[j] = 0.f;
  float ksacc = 0.f;

  for (int ch = s; ch < 49; ch += 8) {
    const size_t tokbase = (size_t)b * MJ + ch * 64;
    __syncthreads();
#pragma unroll
    for (int i = 0; i < 2; ++i) {
      int c = t + i * 256;
      int row = c >> 3, eo = (c & 7) * 8;
      const u16* base = qkv + (tokbase + row) * 2304 + h * 64 + eo;
      *(uint4*)&ks[row * 64 + eo] = *(const uint4*)(base + 768);
      *(uint4*)&vs[row * 64 + eo] = *(const uint4*)(base + 1536);
    }
    __syncthreads();
    for (int m = 0; m < 64; ++m) {
      float kf = b2f(ks[m * 64 + e]);
      ksacc += kf;
      bf16x8 v0 = *(const bf16x8*)&vs[m * 64 + dg];
      bf16x8 v1 = *(const bf16x8*)&vs[m * 64 + dg + 8];
#pragma unroll
      for (int j = 0; j < 8; ++j) {
        acc[j]     += kf * (float)v0[j];
        acc[j + 8] += kf * (float)v1[j];
      }
    }
  }
  float* dst = kv + (size_t)bh * 4096 + e * 64 + dg;
#pragma unroll
  for (int j = 0; j < 16; ++j) atomicAdd(&dst[j], acc[j]);
  if (dg == 0) atomicAdd(&ksum[bh * 64 + e], ksacc);
}

// ---------------- out = (q_ @ kv) * z ----------------
__global__ __launch_bounds__(256) void attn_out(const u16* __restrict__ qkv,
    const float* __restrict__ kv, const float* __restrict__ ksum,
    u16* __restrict__ outp)
{
  const int chunk = blockIdx.x;   // 0..48
  const int h = blockIdx.y;       // 0..11
  const int b = blockIdx.z;       // 0..7
  __shared__ float kvs[4096];
  __shared__ float kss[64];
  const int t = threadIdx.x;
  const float* kvsrc = kv + (size_t)(b * 12 + h) * 4096;
  for (int i = t; i < 1024; i += 256)
    ((float4*)kvs)[i] = ((const float4*)kvsrc)[i];
  if (t < 64) kss[t] = ksum[(b * 12 + h) * 64 + t];
  __syncthreads();
  const int wv = t >> 6, lane = t & 63;
  for (int i = 0; i < 16; ++i) {
    const int m = chunk * 64 + wv * 16 + i;
    const size_t token = (size_t)b * MJ + m;
    float q = b2f(qkv[token * 2304 + h * 64 + lane]);
    float pd = q * kss[lane];
#pragma unroll
    for (int off = 32; off > 0; off >>= 1) pd += __shfl_xor(pd, off, 64);
    const float z = 1.0f / (pd + 1e-6f);
    float o = 0.f;
    for (int e = 0; e < 64; ++e) o += __shfl(q, e, 64) * kvs[e * 64 + lane];
    outp[token * 768 + h * 64 + lane] = f2b(o * z);
  }
}

// ---------------- depthwise 3x3 conv + exact GELU, in place --------------
__global__ __launch_bounds__(256) void dwconv_gelu(u16* __restrict__ hdn,
    const float* __restrict__ w, const float* __restrict__ bias)
{
  __shared__ u16 pl[196 * 64];
  const int cb = blockIdx.x;     // 0..47
  const int fr = blockIdx.y;     // 0..127
  const int t = threadIdx.x;
  const int c0 = cb * 64;
  u16* base = hdn + (size_t)fr * 196 * HID + c0;
  for (int i = 0; i < 49; ++i) {
    int idx = i * 256 + t;
    int p = idx >> 6, c = idx & 63;
    pl[idx] = base[(size_t)p * HID + c];
  }
  __syncthreads();
  const int c = t & 63;
  const int pg = t >> 6;
  float wr[9];
#pragma unroll
  for (int k = 0; k < 9; ++k) wr[k] = w[(c0 + c) * 9 + k];
  const float bv = bias[c0 + c];
  for (int j = 0; j < 49; ++j) {
    const int p = pg + j * 4;
    const int py = p / 14, px = p % 14;
    float a = bv;
#pragma unroll
    for (int ky = 0; ky < 3; ++ky) {
      int yy = py + ky - 1;
      if (yy < 0 || yy > 13) continue;
#pragma unroll
      for (int kx = 0; kx < 3; ++kx) {
        int xx = px + kx - 1;
        if (xx < 0 || xx > 13) continue;
        a += wr[ky * 3 + kx] * b2f(pl[(yy * 14 + xx) * 64 + c]);
      }
    }
    float g = 0.5f * a * (1.0f + erff(a * 0.70710678118654752f));
    base[(size_t)p * HID + c] = f2b(g);
  }
}

extern "C" void kernel_launch(void* const* d_in, const int* in_sizes, int n_in,
                              void* d_out, int out_size, void* d_ws, size_t ws_size,
                              hipStream_t stream)
{
  (void)in_sizes; (void)n_in; (void)out_size;
  const float* x     = (const float*)d_in[0];
  const float* ln1w  = (const float*)d_in[1];
  const float* ln1b  = (const float*)d_in[2];
  const float* qkvw  = (const float*)d_in[3];
  const float* projw = (const float*)d_in[4];
  const float* projb = (const float*)d_in[5];
  const float* ln2w  = (const float*)d_in[6];
  const float* ln2b  = (const float*)d_in[7];
  const float* fc1w  = (const float*)d_in[8];
  const float* fc1b  = (const float*)d_in[9];
  const float* dww   = (const float*)d_in[10];
  const float* dwb   = (const float*)d_in[11];
  const float* fc2w  = (const float*)d_in[12];
  const float* fc2b  = (const float*)d_in[13];

  // constant across calls: same branch every launch
  char* p = (ws_size >= WS_NEED) ? (char*)d_ws : (char*)g_buf;
  u16* WQKV  = (u16*)p;   p += (size_t)2304 * 768 * 2;
  u16* WPROJ = (u16*)p;   p += (size_t)768 * 768 * 2;
  u16* WFC1  = (u16*)p;   p += (size_t)3072 * 768 * 2;
  u16* WFC2  = (u16*)p;   p += (size_t)768 * 3072 * 2;
  u16* XN    = (u16*)p;   p += SZ_XN;    // xn1 / attn_out
  u16* QKV   = (u16*)p;   p += SZ_QKV;   // q_,k_,v  / xn2
  float* X2  = (float*)p; p += SZ_X2;    // residual after attn (fp32)
  u16* HDN   = (u16*)p;   p += SZ_HDN;   // fc1 out, conv in place
  float* KV  = (float*)p; p += SZ_KV;
  float* KS  = (float*)p; p += SZ_KS;

  // convert weights to bf16 (same work every call)
  cvt_f32_bf16<<<(2304*768/4 + 255)/256, 256, 0, stream>>>(qkvw, WQKV, 2304*768/4);
  cvt_f32_bf16<<<(768*768/4 + 255)/256, 256, 0, stream>>>(projw, WPROJ, 768*768/4);
  cvt_f32_bf16<<<(3072*768/4 + 255)/256, 256, 0, stream>>>(fc1w, WFC1, 3072*768/4);
  cvt_f32_bf16<<<(768*3072/4 + 255)/256, 256, 0, stream>>>(fc2w, WFC2, 768*3072/4);

  const int nz = 96 * 4096 + 96 * 64;    // KV and KS are contiguous
  zero_f32<<<(nz + 255) / 256, 256, 0, stream>>>(KV, nz);
  ln_kernel<<<NTOKENS / 4, 256, 0, stream>>>(x, ln1w, ln1b, XN);
  gemm_bt<0><<<dim3(18, 196), 256, 0, stream>>>(XN, WQKV, nullptr, nullptr, QKV, NTOKENS, 2304, 768);
  kv_reduce<<<dim3(96, 8), 256, 0, stream>>>(QKV, KV, KS);
  attn_out<<<dim3(49, 12, 8), 256, 0, stream>>>(QKV, KV, KS, XN);
  gemm_bt<1><<<dim3(6, 196), 256, 0, stream>>>(XN, WPROJ, projb, x, X2, NTOKENS, 768, 768);
  ln_kernel<<<NTOKENS / 4, 256, 0, stream>>>(X2, ln2w, ln2b, QKV);
  gemm_bt<2><<<dim3(24, 196), 256, 0, stream>>>(QKV, WFC1, fc1b, nullptr, HDN, NTOKENS, 3072, 768);
  dwconv_gelu<<<dim3(48, 128), 256, 0, stream>>>(HDN, dww, dwb);
  gemm_bt<3><<<dim3(6, 196), 256, 0, stream>>>(HDN, WFC2, fc2b, X2, (float*)d_out, NTOKENS, 768, 3072);
}

// Round 6
// 1373.734 us; speedup vs baseline: 1.1642x; 1.1380x over previous
//
#include <hip/hip_runtime.h>

typedef unsigned short u16;
typedef unsigned int u32;

typedef __bf16 bf16x8 __attribute__((ext_vector_type(8)));
typedef float f32x4 __attribute__((ext_vector_type(4)));

#define DIM 768
#define HID 3072
#define NTOK 196
#define BT 128
#define NTOKENS (BT * NTOK)   // 25088
#define MJ 3136               // FRAMES * NTOK
#define HEADS 12

// workspace layout sizes (bytes)
#define SZ_WB   ((size_t)(2304*768 + 768*768 + 3072*768 + 768*3072) * 2)  // bf16 weights
#define SZ_XN   ((size_t)NTOKENS * DIM * 2)
#define SZ_QKV  ((size_t)NTOKENS * 2304 * 2)
#define SZ_X2   ((size_t)NTOKENS * DIM * 4)
#define SZ_HDN  ((size_t)NTOKENS * HID * 2)
#define SZ_KV   ((size_t)96 * 4096 * 4)
#define SZ_KS   ((size_t)96 * 64 * 4)
#define WS_NEED (SZ_WB + SZ_XN + SZ_QKV + SZ_X2 + SZ_HDN + SZ_KV + SZ_KS)

// Fallback scratch allocated at dlopen time (hipMalloc is forbidden only
// inside kernel_launch / graph capture). Used iff ws_size < WS_NEED.
static void* g_buf = nullptr;
struct WsInit {
  WsInit() { (void)hipMalloc(&g_buf, WS_NEED); }
};
static WsInit g_wsinit;

__device__ __forceinline__ float b2f(u16 u) {
  union { u32 i; float f; } x; x.i = ((u32)u) << 16; return x.f;
}
__device__ __forceinline__ u16 f2b(float f) {
  u32 x = __float_as_uint(f);
  return (u16)((x + 0x7fffu + ((x >> 16) & 1u)) >> 16);
}

// async 16B global->LDS (gfx950). LDS dest = wave-uniform base + lane*16.
__device__ __forceinline__ void gload_lds16(const u16* g, u16* l) {
  __builtin_amdgcn_global_load_lds(
      (const __attribute__((address_space(1))) u32*)g,
      (__attribute__((address_space(3))) u32*)l, 16, 0, 0);
}

// ---------------- f32 -> bf16 conversion (weights) ----------------
__global__ __launch_bounds__(256) void cvt_f32_bf16(const float* __restrict__ in,
    u16* __restrict__ out, int n4)
{
  int i = blockIdx.x * 256 + threadIdx.x;
  if (i < n4) {
    float4 f = ((const float4*)in)[i];
    ushort4 r;
    r.x = f2b(f.x); r.y = f2b(f.y); r.z = f2b(f.z); r.w = f2b(f.w);
    ((ushort4*)out)[i] = r;
  }
}

// ---------------- zero-fill for KV/KS accumulators ----------------
__global__ __launch_bounds__(256) void zero_f32(float* __restrict__ p, int n) {
  int i = blockIdx.x * 256 + threadIdx.x;
  if (i < n) p[i] = 0.0f;
}

// ---------------- LayerNorm: one wave per token, fp32 in, bf16 out ---------
__global__ __launch_bounds__(256) void ln_kernel(const float* __restrict__ xin,
    const float* __restrict__ w, const float* __restrict__ b, u16* __restrict__ out)
{
  const int token = blockIdx.x * 4 + (threadIdx.x >> 6);
  const int lane = threadIdx.x & 63;
  float v[12];
  const float* x = xin + (size_t)token * DIM;
#pragma unroll
  for (int c = 0; c < 3; ++c) {
    float4 f = *(const float4*)(x + c * 256 + lane * 4);
    v[c*4+0] = f.x; v[c*4+1] = f.y; v[c*4+2] = f.z; v[c*4+3] = f.w;
  }
  float s = 0.f, sq = 0.f;
#pragma unroll
  for (int i = 0; i < 12; ++i) { s += v[i]; sq += v[i] * v[i]; }
#pragma unroll
  for (int off = 32; off > 0; off >>= 1) {
    s += __shfl_xor(s, off, 64);
    sq += __shfl_xor(sq, off, 64);
  }
  const float mean = s * (1.0f / 768.0f);
  const float var = sq * (1.0f / 768.0f) - mean * mean;
  const float rstd = rsqrtf(var + 1e-5f);
  u16* o = out + (size_t)token * DIM;
#pragma unroll
  for (int c = 0; c < 3; ++c) {
    float4 wv = *(const float4*)(w + c * 256 + lane * 4);
    float4 bv = *(const float4*)(b + c * 256 + lane * 4);
    ushort4 r;
    r.x = f2b((v[c*4+0] - mean) * rstd * wv.x + bv.x);
    r.y = f2b((v[c*4+1] - mean) * rstd * wv.y + bv.y);
    r.z = f2b((v[c*4+2] - mean) * rstd * wv.z + bv.z);
    r.w = f2b((v[c*4+3] - mean) * rstd * wv.w + bv.w);
    *(ushort4*)(o + c * 256 + lane * 4) = r;
  }
}

// ---------------- MFMA GEMM: C[M,N] = A[M,K] * W[N,K]^T, fused epilogues ----
// 1-D grid of NX*196 blocks with XCD-aware swizzle: all NX n-tiles of one
// m-row run on ONE XCD so the A-row is fetched from HBM once and L2-hits
// for the rest (cuts traffic ~NX-fold and load latency to ~L2).
// K-loop: double-buffered global_load_lds, one barrier per iter (R5).
// LDS layout per tile: 8 wave-blocks of 1 KB; block = 16 rows x 32 u16,
//   byte addr = chunk*256 + row*16 (conflict-free ds_read_b128 frags).
// MODE 0: QKV  (no bias; relu+0.125 on cols < 1536; bf16 out)
// MODE 1: PROJ (fp32 bias + fp32 residual; fp32 out)
// MODE 2: FC1  (fp32 bias; bf16 out)
// MODE 3: FC2  (fp32 bias + fp32 residual; fp32 out)
template<int MODE, int NX, int NN, int KK>
__global__ __launch_bounds__(256) void gemm_bt(
    const u16* __restrict__ A, const u16* __restrict__ W,
    const float* __restrict__ bias, const float* __restrict__ res,
    void* __restrict__ out)
{
  __shared__ __align__(16) u16 As[2][128 * 32];   // 2 x 8 KB
  __shared__ __align__(16) u16 Bs[2][128 * 32];   // 2 x 8 KB
  const int t = threadIdx.x;
  const int lane = t & 63;
  const int wv = t >> 6;            // 0..3

  // XCD swizzle: hw round-robins consecutive block ids across 8 XCDs.
  constexpr int TOTAL = NX * 196;
  constexpr int CHUNK = TOTAL / 8;
  const int f = blockIdx.x;
  const int work = (f & 7) * CHUNK + (f >> 3);
  const int m0 = (work / NX) * 128;
  const int n0 = (work % NX) * 128;

  // staging: wave wv stages A wave-blocks {2wv,2wv+1} and same for B.
  const int srow = lane & 15;
  const int schunk = lane >> 4;
  const u16* gA0 = A + (size_t)(m0 + 2 * wv * 16 + srow) * KK + schunk * 8;
  const u16* gA1 = A + (size_t)(m0 + (2 * wv + 1) * 16 + srow) * KK + schunk * 8;
  const u16* gB0 = W + (size_t)(n0 + 2 * wv * 16 + srow) * KK + schunk * 8;
  const u16* gB1 = W + (size_t)(n0 + (2 * wv + 1) * 16 + srow) * KK + schunk * 8;
  const int lo0 = (2 * wv) * 512;
  const int lo1 = (2 * wv + 1) * 512;

  const int lm = lane & 15;
  const int q = lane >> 4;
  const int ab = (wv & 1) * 4;      // A wave-block base for compute
  const int bb = (wv >> 1) * 4;     // B wave-block base

  f32x4 acc[4][4];
#pragma unroll
  for (int i = 0; i < 4; ++i)
#pragma unroll
    for (int j = 0; j < 4; ++j) acc[i][j] = (f32x4){0.f, 0.f, 0.f, 0.f};

  constexpr int nt = KK >> 5;
  // prologue: stage tile 0 into buffer 0
  gload_lds16(gA0, &As[0][lo0]);
  gload_lds16(gA1, &As[0][lo1]);
  gload_lds16(gB0, &Bs[0][lo0]);
  gload_lds16(gB1, &Bs[0][lo1]);

  for (int ti = 0; ti < nt; ++ti) {
    __syncthreads();   // drains tile-ti loads (vmcnt) + prev buffer reads
    const int cur = ti & 1;
    if (ti + 1 < nt) {
      const int k1 = (ti + 1) << 5;
      const int nxt = cur ^ 1;
      gload_lds16(gA0 + k1, &As[nxt][lo0]);
      gload_lds16(gA1 + k1, &As[nxt][lo1]);
      gload_lds16(gB0 + k1, &Bs[nxt][lo0]);
      gload_lds16(gB1 + k1, &Bs[nxt][lo1]);
    }
    bf16x8 af[4], bfv[4];
#pragma unroll
    for (int mi = 0; mi < 4; ++mi)
      af[mi] = *(const bf16x8*)&As[cur][(ab + mi) * 512 + q * 128 + lm * 8];
#pragma unroll
    for (int ni = 0; ni < 4; ++ni)
      bfv[ni] = *(const bf16x8*)&Bs[cur][(bb + ni) * 512 + q * 128 + lm * 8];
#pragma unroll
    for (int mi = 0; mi < 4; ++mi)
#pragma unroll
      for (int ni = 0; ni < 4; ++ni)
        acc[mi][ni] = __builtin_amdgcn_mfma_f32_16x16x32_bf16(af[mi], bfv[ni], acc[mi][ni], 0, 0, 0);
  }

  const int wm = (wv & 1) << 6;
  const int wn = (wv >> 1) << 6;
#pragma unroll
  for (int mi = 0; mi < 4; ++mi) {
    const int rbase = m0 + wm + mi * 16 + q * 4;
#pragma unroll
    for (int ni = 0; ni < 4; ++ni) {
      const int col = n0 + wn + ni * 16 + lm;
      float bv = 0.f;
      if (MODE != 0) bv = bias[col];
#pragma unroll
      for (int r = 0; r < 4; ++r) {
        float v = acc[mi][ni][r];
        const size_t idx = (size_t)(rbase + r) * NN + col;
        if (MODE == 0) {
          if (col < 1536) v = fmaxf(v, 0.0f) + 0.125f;
          ((u16*)out)[idx] = f2b(v);
        } else if (MODE == 1) {
          ((float*)out)[idx] = v + bv + res[idx];
        } else if (MODE == 2) {
          ((u16*)out)[idx] = f2b(v + bv);
        } else {
          ((float*)out)[idx] = v + bv + res[idx];
        }
      }
    }
  }
}

// ---------------- kv = sum_m k_ (outer) v ; ksum = sum_m k_  ----------------
// grid (96, 8): bh pair, m-split. Accumulate with fp32 atomics.
__global__ __launch_bounds__(256) void kv_reduce(const u16* __restrict__ qkv,
    float* __restrict__ kv, float* __restrict__ ksum)
{
  const int bh = blockIdx.x;       // b*12+h
  const int s = blockIdx.y;        // 0..7
  const int b = bh / 12, h = bh % 12;
  __shared__ __align__(16) u16 ks[64 * 64];
  __shared__ __align__(16) u16 vs[64 * 64];
  const int t = threadIdx.x;
  const int e = t & 63;
  const int dg = (t >> 6) * 16;

  float acc[16];
#pragma unroll
  for (int j = 0; j < 16; ++j) acc[j] = 0.f;
  float ksacc = 0.f;

  for (int ch = s; ch < 49; ch += 8) {
    const size_t tokbase = (size_t)b * MJ + ch * 64;
    __syncthreads();
#pragma unroll
    for (int i = 0; i < 2; ++i) {
      int c = t + i * 256;
      int row = c >> 3, eo = (c & 7) * 8;
      const u16* base = qkv + (tokbase + row) * 2304 + h * 64 + eo;
      *(uint4*)&ks[row * 64 + eo] = *(const uint4*)(base + 768);
      *(uint4*)&vs[row * 64 + eo] = *(const uint4*)(base + 1536);
    }
    __syncthreads();
    for (int m = 0; m < 64; ++m) {
      float kf = b2f(ks[m * 64 + e]);
      ksacc += kf;
      bf16x8 v0 = *(const bf16x8*)&vs[m * 64 + dg];
      bf16x8 v1 = *(const bf16x8*)&vs[m * 64 + dg + 8];
#pragma unroll
      for (int j = 0; j < 8; ++j) {
        acc[j]     += kf * (float)v0[j];
        acc[j + 8] += kf * (float)v1[j];
      }
    }
  }
  float* dst = kv + (size_t)bh * 4096 + e * 64 + dg;
#pragma unroll
  for (int j = 0; j < 16; ++j) atomicAdd(&dst[j], acc[j]);
  if (dg == 0) atomicAdd(&ksum[bh * 64 + e], ksacc);
}

// ---------------- out = (q_ @ kv) * z ----------------
// Per wave: 16 tokens. Pre-scale q by z, stage in LDS, then accumulate all
// 16 tokens against each kv column (halves LDS ops vs shuffle matvec).
__global__ __launch_bounds__(256) void attn_out(const u16* __restrict__ qkv,
    const float* __restrict__ kv, const float* __restrict__ ksum,
    u16* __restrict__ outp)
{
  const int chunk = blockIdx.x;   // 0..48
  const int h = blockIdx.y;       // 0..11
  const int b = blockIdx.z;       // 0..7
  __shared__ float kvs[4096];
  __shared__ float kss[64];
  __shared__ float qs[4096];      // [wave][16 tok][64 e]
  const int t = threadIdx.x;
  const float* kvsrc = kv + (size_t)(b * 12 + h) * 4096;
  for (int i = t; i < 1024; i += 256)
    ((float4*)kvs)[i] = ((const float4*)kvsrc)[i];
  if (t < 64) kss[t] = ksum[(b * 12 + h) * 64 + t];
  __syncthreads();
  const int wv = t >> 6, lane = t & 63;
  float* qw = &qs[wv * 1024];
  const size_t tok0 = (size_t)b * MJ + chunk * 64 + wv * 16;
#pragma unroll
  for (int i = 0; i < 16; ++i) {
    float q = b2f(qkv[(tok0 + i) * 2304 + h * 64 + lane]);
    float pd = q * kss[lane];
#pragma unroll
    for (int off = 32; off > 0; off >>= 1) pd += __shfl_xor(pd, off, 64);
    qw[i * 64 + lane] = q * (1.0f / (pd + 1e-6f));
  }
  float o[16];
#pragma unroll
  for (int i = 0; i < 16; ++i) o[i] = 0.f;
  for (int e = 0; e < 64; ++e) {
    const float kvc = kvs[e * 64 + lane];
#pragma unroll
    for (int i = 0; i < 16; ++i) o[i] += qw[i * 64 + e] * kvc;
  }
#pragma unroll
  for (int i = 0; i < 16; ++i)
    outp[(tok0 + i) * 768 + h * 64 + lane] = f2b(o[i]);
}

// ---------------- depthwise 3x3 conv + exact GELU, in place --------------
__global__ __launch_bounds__(256) void dwconv_gelu(u16* __restrict__ hdn,
    const float* __restrict__ w, const float* __restrict__ bias)
{
  __shared__ u16 pl[196 * 64];
  const int cb = blockIdx.x;     // 0..47
  const int fr = blockIdx.y;     // 0..127
  const int t = threadIdx.x;
  const int c0 = cb * 64;
  u16* base = hdn + (size_t)fr * 196 * HID + c0;
  for (int i = 0; i < 49; ++i) {
    int idx = i * 256 + t;
    int p = idx >> 6, c = idx & 63;
    pl[idx] = base[(size_t)p * HID + c];
  }
  __syncthreads();
  const int c = t & 63;
  const int pg = t >> 6;
  float wr[9];
#pragma unroll
  for (int k = 0; k < 9; ++k) wr[k] = w[(c0 + c) * 9 + k];
  const float bv = bias[c0 + c];
  for (int j = 0; j < 49; ++j) {
    const int p = pg + j * 4;
    const int py = p / 14, px = p % 14;
    float a = bv;
#pragma unroll
    for (int ky = 0; ky < 3; ++ky) {
      int yy = py + ky - 1;
      if (yy < 0 || yy > 13) continue;
#pragma unroll
      for (int kx = 0; kx < 3; ++kx) {
        int xx = px + kx - 1;
        if (xx < 0 || xx > 13) continue;
        a += wr[ky * 3 + kx] * b2f(pl[(yy * 14 + xx) * 64 + c]);
      }
    }
    float g = 0.5f * a * (1.0f + erff(a * 0.70710678118654752f));
    base[(size_t)p * HID + c] = f2b(g);
  }
}

extern "C" void kernel_launch(void* const* d_in, const int* in_sizes, int n_in,
                              void* d_out, int out_size, void* d_ws, size_t ws_size,
                              hipStream_t stream)
{
  (void)in_sizes; (void)n_in; (void)out_size;
  const float* x     = (const float*)d_in[0];
  const float* ln1w  = (const float*)d_in[1];
  const float* ln1b  = (const float*)d_in[2];
  const float* qkvw  = (const float*)d_in[3];
  const float* projw = (const float*)d_in[4];
  const float* projb = (const float*)d_in[5];
  const float* ln2w  = (const float*)d_in[6];
  const float* ln2b  = (const float*)d_in[7];
  const float* fc1w  = (const float*)d_in[8];
  const float* fc1b  = (const float*)d_in[9];
  const float* dww   = (const float*)d_in[10];
  const float* dwb   = (const float*)d_in[11];
  const float* fc2w  = (const float*)d_in[12];
  const float* fc2b  = (const float*)d_in[13];

  // constant across calls: same branch every launch
  char* p = (ws_size >= WS_NEED) ? (char*)d_ws : (char*)g_buf;
  u16* WQKV  = (u16*)p;   p += (size_t)2304 * 768 * 2;
  u16* WPROJ = (u16*)p;   p += (size_t)768 * 768 * 2;
  u16* WFC1  = (u16*)p;   p += (size_t)3072 * 768 * 2;
  u16* WFC2  = (u16*)p;   p += (size_t)768 * 3072 * 2;
  u16* XN    = (u16*)p;   p += SZ_XN;    // xn1 / attn_out
  u16* QKV   = (u16*)p;   p += SZ_QKV;   // q_,k_,v  / xn2
  float* X2  = (float*)p; p += SZ_X2;    // residual after attn (fp32)
  u16* HDN   = (u16*)p;   p += SZ_HDN;   // fc1 out, conv in place
  float* KV  = (float*)p; p += SZ_KV;
  float* KS  = (float*)p; p += SZ_KS;

  // convert weights to bf16 (same work every call)
  cvt_f32_bf16<<<(2304*768/4 + 255)/256, 256, 0, stream>>>(qkvw, WQKV, 2304*768/4);
  cvt_f32_bf16<<<(768*768/4 + 255)/256, 256, 0, stream>>>(projw, WPROJ, 768*768/4);
  cvt_f32_bf16<<<(3072*768/4 + 255)/256, 256, 0, stream>>>(fc1w, WFC1, 3072*768/4);
  cvt_f32_bf16<<<(768*3072/4 + 255)/256, 256, 0, stream>>>(fc2w, WFC2, 768*3072/4);

  const int nz = 96 * 4096 + 96 * 64;    // KV and KS are contiguous
  zero_f32<<<(nz + 255) / 256, 256, 0, stream>>>(KV, nz);
  ln_kernel<<<NTOKENS / 4, 256, 0, stream>>>(x, ln1w, ln1b, XN);
  gemm_bt<0, 18, 2304, 768><<<18 * 196, 256, 0, stream>>>(XN, WQKV, nullptr, nullptr, QKV);
  kv_reduce<<<dim3(96, 8), 256, 0, stream>>>(QKV, KV, KS);
  attn_out<<<dim3(49, 12, 8), 256, 0, stream>>>(QKV, KV, KS, XN);
  gemm_bt<1, 6, 768, 768><<<6 * 196, 256, 0, stream>>>(XN, WPROJ, projb, x, X2);
  ln_kernel<<<NTOKENS / 4, 256, 0, stream>>>(X2, ln2w, ln2b, QKV);
  gemm_bt<2, 24, 3072, 768><<<24 * 196, 256, 0, stream>>>(QKV, WFC1, fc1b, nullptr, HDN);
  dwconv_gelu<<<dim3(48, 128), 256, 0, stream>>>(HDN, dww, dwb);
  gemm_bt<3, 6, 768, 3072><<<6 * 196, 256, 0, stream>>>(HDN, WFC2, fc2b, X2, (float*)d_out);
}